// Round 13
// baseline (1020.553 us; speedup 1.0000x reference)
//
#include <hip/hip_runtime.h>

#define HWN 16384
#define DMODEL 512
#define NLANG 20
#define LCH 768
#define NB 8
#define MTOT (NB*HWN)
#define NHEADS 8

typedef float floatx4 __attribute__((ext_vector_type(4)));
typedef short short8 __attribute__((ext_vector_type(8)));

__device__ __forceinline__ float bflo(unsigned u){ return __uint_as_float(u << 16); }
__device__ __forceinline__ float bfhi(unsigned u){ return __uint_as_float(u & 0xffff0000u); }
__device__ __forceinline__ unsigned short f2bf(float f){
  unsigned u = __float_as_uint(f);
  u += 0x7fffu + ((u >> 16) & 1u);
  return (unsigned short)(u >> 16);
}
__device__ __forceinline__ unsigned pack2(float a, float b){
  return (unsigned)f2bf(a) | ((unsigned)f2bf(b) << 16);
}
// tanh-form GELU (max |err| vs exact ~5e-4)
__device__ __forceinline__ float geluf(float v){
  float t = v * v;
  float u2 = v * fmaf(t, -0.0713548162f, -1.5957691216f); // -2*u
  float e = __expf(u2);
  return v * __builtin_amdgcn_rcpf(1.0f + e);
}
__device__ __forceinline__ void stage16(const void* g, void* l){
  __builtin_amdgcn_global_load_lds(
      (const __attribute__((address_space(1))) void*)g,
      (__attribute__((address_space(3))) void*)l, 16, 0, 0);
}
// transpose-within-row chunk permutation: chunk c (0..63) -> slot ((c&7)<<3)|(c>>3)
__device__ __forceinline__ int tslot(int c){ return ((c & 7) << 3) | (c >> 3); }

// ---------------- prep: transpose weights to [N][K] bf16 ----------------
__global__ void prep_w(const float* __restrict__ Wv, const float* __restrict__ Wq,
                       const float* __restrict__ Ww, const float* __restrict__ Wm,
                       unsigned short* __restrict__ wcatT, unsigned short* __restrict__ wwT,
                       unsigned short* __restrict__ wmT)
{
  int i = blockIdx.x * 256 + threadIdx.x;
  if (i < 1024 * 512) {
    int n = i >> 9, k = i & 511;
    float v = (n < 512) ? Wv[k * 512 + n] : Wq[k * 512 + (n - 512)];
    wcatT[i] = f2bf(v);
  } else {
    int j = i - 1024 * 512;
    if (j < 512 * 512) { int n = j >> 9, k = j & 511; wwT[j] = f2bf(Ww[k * 512 + n]); }
    else { j -= 512 * 512; int n = j >> 9, k = j & 511; wmT[j] = f2bf(Wm[k * 512 + n]); }
  }
}

// ---------------- x fp32 -> bf16 ----------------
__global__ void xcvt(const float* __restrict__ x, unsigned short* __restrict__ xb)
{
  size_t i = ((size_t)blockIdx.x * 256 + threadIdx.x) * 8;
  float4 a = *reinterpret_cast<const float4*>(&x[i]);
  float4 b = *reinterpret_cast<const float4*>(&x[i + 4]);
  uint4 d;
  d.x = pack2(a.x, a.y); d.y = pack2(a.z, a.w);
  d.z = pack2(b.x, b.y); d.w = pack2(b.z, b.w);
  *reinterpret_cast<uint4*>(&xb[i]) = d;
}

// ---------------- mm = vis * (y*a + b) ----------------
__global__ void mmk(const unsigned short* __restrict__ y, const unsigned short* __restrict__ vis,
                    const float* __restrict__ lma, const float* __restrict__ lmb,
                    unsigned short* __restrict__ mm)
{
  size_t i = ((size_t)blockIdx.x * 256 + threadIdx.x) * 8;
  int c = (int)(i & 511);
  int b = (int)(i >> 23);
  uint4 yv = *reinterpret_cast<const uint4*>(&y[i]);
  uint4 vv = *reinterpret_cast<const uint4*>(&vis[i]);
  const float* Ap = &lma[b * 512 + c];
  const float* Bp = &lmb[b * 512 + c];
  float4 a0 = *reinterpret_cast<const float4*>(Ap);
  float4 a1 = *reinterpret_cast<const float4*>(Ap + 4);
  float4 b0 = *reinterpret_cast<const float4*>(Bp);
  float4 b1 = *reinterpret_cast<const float4*>(Bp + 4);
  float m0 = bflo(vv.x) * (bflo(yv.x) * a0.x + b0.x);
  float m1 = bfhi(vv.x) * (bfhi(yv.x) * a0.y + b0.y);
  float m2 = bflo(vv.y) * (bflo(yv.y) * a0.z + b0.z);
  float m3 = bfhi(vv.y) * (bfhi(yv.y) * a0.w + b0.w);
  float m4 = bflo(vv.z) * (bflo(yv.z) * a1.x + b1.x);
  float m5 = bfhi(vv.z) * (bfhi(yv.z) * a1.y + b1.y);
  float m6 = bflo(vv.w) * (bflo(yv.w) * a1.z + b1.z);
  float m7 = bfhi(vv.w) * (bfhi(yv.w) * a1.w + b1.w);
  uint4 d;
  d.x = pack2(m0, m1); d.y = pack2(m2, m3);
  d.z = pack2(m4, m5); d.w = pack2(m6, m7);
  *reinterpret_cast<uint4*>(&mm[i]) = d;
}

// ---------------- prep: k = l@Wk+bk (fp32), v = l@Wval+bval (bf16, tslot layout) ----------------
__global__ void prep_kv(const float* __restrict__ l, const float* __restrict__ Wk,
                        const float* __restrict__ bk, const float* __restrict__ Wval,
                        const float* __restrict__ bval,
                        float* __restrict__ kraw, unsigned short* __restrict__ vb)
{
  int i = blockIdx.x * 256 + threadIdx.x;
  int which = i / (NB * NLANG * 512);
  int j = i - which * (NB * NLANG * 512);
  int bt = j >> 9;
  int c = j & 511;
  const float* W = which ? Wval : Wk;
  float acc = which ? bval[c] : bk[c];
  const float* lr = l + (size_t)bt * LCH;
  for (int p = 0; p < LCH; p++) acc = fmaf(lr[p], W[p * 512 + c], acc);
  if (which) {
    int cnk = c >> 3, e = c & 7;
    vb[bt * 512 + tslot(cnk) * 8 + e] = f2bf(acc);
  } else {
    kraw[j] = acc;
  }
}

// ---------------- fold q-instance-norm into k' (tslot layout) ----------------
__global__ void kprep(const float* __restrict__ qsum, const float* __restrict__ qsq,
                      const float* __restrict__ kraw, unsigned short* __restrict__ kp,
                      float* __restrict__ offG)
{
  int blk = blockIdx.x; int b = blk / NLANG, t = blk - b * NLANG;
  int lane = threadIdx.x;
  float offp = 0.f;
  float vals[8];
  #pragma unroll
  for (int e = 0; e < 8; e++) {
    int c = lane * 8 + e;
    float mean = qsum[b * 512 + c] * (1.f / 16384.f);
    float var  = qsq[b * 512 + c] * (1.f / 16384.f) - mean * mean;
    float inv  = rsqrtf(var + 1e-5f);
    float a = inv * 0.044194173824159216f;
    float kv = kraw[((size_t)(b * NLANG + t)) * 512 + c];
    vals[e] = kv * a;
    offp += (-mean * a) * kv;
  }
  unsigned u0 = pack2(vals[0], vals[1]);
  unsigned u1 = pack2(vals[2], vals[3]);
  unsigned u2 = pack2(vals[4], vals[5]);
  unsigned u3 = pack2(vals[6], vals[7]);
  uint4 uu = make_uint4(u0, u1, u2, u3);
  *reinterpret_cast<uint4*>(&kp[((size_t)(b * NLANG + t)) * 512 + tslot(lane) * 8]) = uu;
  offp += __shfl_xor(offp, 1);
  offp += __shfl_xor(offp, 2);
  offp += __shfl_xor(offp, 4);
  if ((lane & 7) == 0) offG[(b * 8 + (lane >> 3)) * NLANG + t] = offp;
}

// ---------------- lang-norm coefficients ----------------
__global__ void lmk(const float* __restrict__ ysum, const float* __restrict__ ysq,
                    float* __restrict__ lma, float* __restrict__ lmb)
{
  int i = blockIdx.x * 256 + threadIdx.x;
  if (i < NB * 512) {
    float mean = ysum[i] * (1.f / 16384.f);
    float var  = ysq[i] * (1.f / 16384.f) - mean * mean;
    float inv  = rsqrtf(var + 1e-5f);
    lma[i] = inv; lmb[i] = -mean * inv;
  }
}

// ---------------- attention (unchanged, proven) ----------------
__global__ __launch_bounds__(256, 2) void attn_k(
    const unsigned short* __restrict__ kp, const unsigned short* __restrict__ vbg,
    const float* __restrict__ offG, unsigned short* __restrict__ qb)
{
  __shared__ __align__(16) unsigned short kps[NLANG * 512];
  __shared__ __align__(16) unsigned short vbs[NLANG * 512];
  __shared__ __align__(16) unsigned short qs[32 * 512];
  __shared__ float offs[NHEADS * NLANG];
  int tid = threadIdx.x, bid = blockIdx.x;
  int b = bid >> 9;
  int row0 = (bid & 511) * 32;
  size_t base = (size_t)b * (NLANG * 512);
  const uint4* kg = reinterpret_cast<const uint4*>(kp + base);
  const uint4* vg = reinterpret_cast<const uint4*>(vbg + base);
  uint4* kl = reinterpret_cast<uint4*>(kps);
  uint4* vl = reinterpret_cast<uint4*>(vbs);
  #pragma unroll
  for (int i = 0; i < 5; i++) { int o = i * 256 + tid; kl[o] = kg[o]; vl[o] = vg[o]; }
  if (tid < NHEADS * NLANG) offs[tid] = offG[b * (NHEADS * NLANG) + tid];

  size_t grow0 = (size_t)b * HWN + row0;
  #pragma unroll
  for (int i = 0; i < 8; i++) {
    int g = i * 256 + tid;
    int row = g >> 6, c = g & 63;
    uint4 d = *reinterpret_cast<const uint4*>(&qb[(grow0 + row) * 512 + c * 8]);
    *reinterpret_cast<uint4*>(&qs[row * 512 + tslot(c) * 8]) = d;
  }
  __syncthreads();

  int r = tid >> 3, h = tid & 7;
  float sim[NLANG];
  #pragma unroll
  for (int t = 0; t < NLANG; t++) sim[t] = offs[h * NLANG + t];
  #pragma unroll
  for (int j = 0; j < 8; j++) {
    uint4 qv = *reinterpret_cast<const uint4*>(&qs[r * 512 + (j * 8 + h) * 8]);
    float q0 = bflo(qv.x), q1 = bfhi(qv.x), q2 = bflo(qv.y), q3 = bfhi(qv.y);
    float q4 = bflo(qv.z), q5 = bfhi(qv.z), q6 = bflo(qv.w), q7 = bfhi(qv.w);
    #pragma unroll
    for (int t = 0; t < NLANG; t++) {
      uint4 kv = *reinterpret_cast<const uint4*>(&kps[t * 512 + (j * 8 + h) * 8]);
      float a = sim[t];
      a = fmaf(q0, bflo(kv.x), a); a = fmaf(q1, bfhi(kv.x), a);
      a = fmaf(q2, bflo(kv.y), a); a = fmaf(q3, bfhi(kv.y), a);
      a = fmaf(q4, bflo(kv.z), a); a = fmaf(q5, bfhi(kv.z), a);
      a = fmaf(q6, bflo(kv.w), a); a = fmaf(q7, bfhi(kv.w), a);
      sim[t] = a;
    }
  }
  float mx = sim[0];
  #pragma unroll
  for (int t = 1; t < NLANG; t++) mx = fmaxf(mx, sim[t]);
  float s = 0.f;
  #pragma unroll
  for (int t = 0; t < NLANG; t++) { float e = __expf(sim[t] - mx); sim[t] = e; s += e; }
  float invs = 1.f / s;
  #pragma unroll
  for (int t = 0; t < NLANG; t++) sim[t] *= invs;

  float o[8][8];
  #pragma unroll
  for (int a2 = 0; a2 < 8; a2++)
    #pragma unroll
    for (int b2 = 0; b2 < 8; b2++) o[a2][b2] = 0.f;
  #pragma unroll
  for (int t = 0; t < NLANG; t++) {
    float p = sim[t];
    #pragma unroll
    for (int j = 0; j < 8; j++) {
      uint4 v4 = *reinterpret_cast<const uint4*>(&vbs[t * 512 + (j * 8 + h) * 8]);
      o[j][0] = fmaf(p, bflo(v4.x), o[j][0]); o[j][1] = fmaf(p, bfhi(v4.x), o[j][1]);
      o[j][2] = fmaf(p, bflo(v4.y), o[j][2]); o[j][3] = fmaf(p, bfhi(v4.y), o[j][3]);
      o[j][4] = fmaf(p, bflo(v4.z), o[j][4]); o[j][5] = fmaf(p, bfhi(v4.z), o[j][5]);
      o[j][6] = fmaf(p, bflo(v4.w), o[j][6]); o[j][7] = fmaf(p, bfhi(v4.w), o[j][7]);
    }
  }
  #pragma unroll
  for (int j = 0; j < 8; j++) {
    uint4 u;
    u.x = pack2(o[j][0], o[j][1]); u.y = pack2(o[j][2], o[j][3]);
    u.z = pack2(o[j][4], o[j][5]); u.w = pack2(o[j][6], o[j][7]);
    *reinterpret_cast<uint4*>(&qs[r * 512 + (j * 8 + h) * 8]) = u;
  }
  __syncthreads();
  #pragma unroll
  for (int i = 0; i < 8; i++) {
    int g = i * 256 + tid;
    int row = g >> 6, c = g & 63;
    uint4 d = *reinterpret_cast<const uint4*>(&qs[row * 512 + tslot(c) * 8]);
    *reinterpret_cast<uint4*>(&qb[(grow0 + row) * 512 + c * 8]) = d;
  }
}

// ---------------- gemm8: 256x256 tile, BK=64, 8 waves, phase-interleaved (mode-0 only) ------
// Ring: 2 K-tile buffers; group g (4 phases) reads tile g, stages tile g+1 into the buffer
// freed at the previous boundary. Fused vmcnt+barrier at boundaries; plain barriers between
// phases; setprio around MFMA clusters.
__global__ __launch_bounds__(512, 2) void gemm8(
    const unsigned short* __restrict__ A,
    const unsigned short* __restrict__ Bw,
    const float* __restrict__ bias0, const float* __restrict__ bias1,
    unsigned short* __restrict__ Out0, unsigned short* __restrict__ Out1,
    float* __restrict__ sum1, float* __restrict__ sum2)
{
  constexpr int NWG = 2048;
  // 128 KB: A slots 0..3 at s*8192 (ushorts), B slots at 32768 + s*8192.
  // Slot = [128 rows][64 k] bf16 (16 KB). K-tile t uses slots {2(t&1), 2(t&1)+1}.
  __shared__ __align__(16) unsigned short SM[65536];

  int raw = blockIdx.x;
  int lid = (raw & 7) * (NWG / 8) + (raw >> 3); // XCD-contiguous, bijective (2048%8==0)
  int tileN = lid & 3;
  int tileM = lid >> 2;
  int tm = tileM * 256;
  int b512 = (tileM >> 6) * 512;               // 64 M-tiles per batch
  int tid = threadIdx.x;
  int wave = tid >> 6, lane = tid & 63;
  int wm = wave >> 2, wn = wave & 3;           // wave out: rows wm*128+[0,128), cols wn*64+[0,64)
  int r15 = lane & 15, kcg = lane >> 4;

  floatx4 acc[8][4];
  floatx4 zz = {0.f, 0.f, 0.f, 0.f};
  #pragma unroll
  for (int m = 0; m < 8; m++)
    #pragma unroll
    for (int n = 0; n < 4; n++) acc[m][n] = zz;

  const unsigned short* Ab = A + (size_t)tm * 512;
  const unsigned short* Bb = Bw + (size_t)(tileN * 256) * 512;

  // stage one half-tile (16 KB): X=0 A, X=1 B; 2 insts/thread.
  // LDS[row][c8] = G[row][c8 ^ (row&7)] (swizzled source, linear dest).
  auto stageH = [&](int t, int X, int h) {
    const unsigned short* G = X ? Bb : Ab;
    unsigned short* L = SM + X * 32768 + ((t & 1) * 2 + h) * 8192;
    #pragma unroll
    for (int i = 0; i < 2; i++) {
      int c = i * 512 + tid;                 // 16B chunk 0..1023
      int row = c >> 3, c8 = c & 7;
      stage16(&G[(size_t)(h * 128 + row) * 512 + t * 64 + (c8 ^ (row & 7)) * 8],
              &L[c * 8]);
    }
  };

  // prologue: tiles 0 and 1 (8 insts each)
  stageH(0, 0, 0); stageH(0, 0, 1); stageH(0, 1, 0); stageH(0, 1, 1);
  stageH(1, 0, 0); stageH(1, 0, 1); stageH(1, 1, 0); stageH(1, 1, 1);
  __builtin_amdgcn_sched_barrier(0);
  asm volatile("s_waitcnt vmcnt(8)\n\ts_barrier" ::: "memory"); // tile 0 landed
  __builtin_amdgcn_sched_barrier(0);

  for (int t = 0; t < 8; t++) {
    const unsigned short* Asl = SM + ((t & 1) * 2 + wm) * 8192;
    const unsigned short* Bsl = SM + 32768 + ((t & 1) * 2 + (wn >> 1)) * 8192;
    int brow0 = (wn & 1) * 64;
    #pragma unroll
    for (int p = 0; p < 4; p++) {
      int qm = p >> 1, qn = p & 1;
      // stage tile t+1 (its buffer was freed at the previous boundary):
      // phase 0: both A halves; phase 1: both B halves. Tiles 2..7 only.
      if (t >= 1 && t < 7) {
        if (p == 0)      { stageH(t + 1, 0, 0); stageH(t + 1, 0, 1); }
        else if (p == 1) { stageH(t + 1, 1, 0); stageH(t + 1, 1, 1); }
      }
      short8 af[4][2], bf[2][2];
      #pragma unroll
      for (int mf = 0; mf < 4; mf++) {
        int row = (qm * 4 + mf) * 16 + r15;
        #pragma unroll
        for (int kk = 0; kk < 2; kk++)
          af[mf][kk] = *reinterpret_cast<const short8*>(
              &Asl[row * 64 + ((kk * 4 + kcg) ^ (row & 7)) * 8]);
      }
      #pragma unroll
      for (int nf = 0; nf < 2; nf++) {
        int row = brow0 + (qn * 2 + nf) * 16 + r15;
        #pragma unroll
        for (int kk = 0; kk < 2; kk++)
          bf[nf][kk] = *reinterpret_cast<const short8*>(
              &Bsl[row * 64 + ((kk * 4 + kcg) ^ (row & 7)) * 8]);
      }
      __builtin_amdgcn_s_setprio(1);
      #pragma unroll
      for (int kk = 0; kk < 2; kk++)
        #pragma unroll
        for (int mf = 0; mf < 4; mf++)
          #pragma unroll
          for (int nf = 0; nf < 2; nf++)
            acc[qm * 4 + mf][qn * 2 + nf] = __builtin_amdgcn_mfma_f32_16x16x32_bf16(
                af[mf][kk], bf[nf][kk], acc[qm * 4 + mf][qn * 2 + nf], 0, 0, 0);
      __builtin_amdgcn_s_setprio(0);
      if (p < 3) {
        __builtin_amdgcn_sched_barrier(0);
        __builtin_amdgcn_s_barrier();
        __builtin_amdgcn_sched_barrier(0);
      }
    }
    // boundary: tile t+1 (issued >=3 phases ago) must be landed before next group reads it.
    __builtin_amdgcn_sched_barrier(0);
    if (t < 7) asm volatile("s_waitcnt vmcnt(0)\n\ts_barrier" ::: "memory");
    __builtin_amdgcn_sched_barrier(0);
  }
  __syncthreads(); // all LDS reads done; reuse SM as C[256][256]

  unsigned short* C = SM;
  int baseR = wm * 128 + kcg * 4;
  #pragma unroll
  for (int nf = 0; nf < 4; nf++) {
    int lcol = wn * 64 + nf * 16 + r15;
    int gcol = tileN * 256 + lcol;
    float s1 = 0.f, s2 = 0.f;
    #pragma unroll
    for (int mf = 0; mf < 8; mf++) {
      #pragma unroll
      for (int j = 0; j < 4; j++) {
        int lrow = baseR + mf * 16 + j;
        float v = acc[mf][nf][j];
        if (tileN < 2) {
          v = geluf(v + bias0[gcol]);
        } else {
          v += bias1[gcol - 512];
          s1 += v; s2 += v * v;
        }
        C[lrow * 256 + (lcol ^ (((lrow >> 2) & 3) << 4))] = f2bf(v);
      }
    }
    if (tileN >= 2) {
      s1 += __shfl_xor(s1, 16); s1 += __shfl_xor(s1, 32);
      s2 += __shfl_xor(s2, 16); s2 += __shfl_xor(s2, 32);
      if (lane < 16) {
        atomicAdd(&sum1[b512 + gcol - 512], s1);
        atomicAdd(&sum2[b512 + gcol - 512], s2);
      }
    }
  }
  __syncthreads();
  unsigned short* Og;
  int colbase;
  if (tileN < 2) { Og = Out0; colbase = tileN * 256; }
  else           { Og = Out1; colbase = (tileN - 2) * 256; }
  #pragma unroll
  for (int tt = 0; tt < 16; tt++) {
    int cid = tt * 512 + tid;
    int row = cid >> 5, cc = cid & 31;     // 256 rows x 32 16B-chunks
    uint4 d = *reinterpret_cast<const uint4*>(
        &C[row * 256 + ((cc * 8) ^ (((row >> 2) & 3) << 4))]);
    *reinterpret_cast<uint4*>(&Og[(size_t)(tm + row) * 512 + colbase + cc * 8]) = d;
  }
}

// ---------------- GEMM: 128x128 tile (r9 proven; used for modes 1 and 2) ----------------
template<int MODE>
__global__ __launch_bounds__(256) void gemm_k(
    const unsigned short* __restrict__ A,
    const unsigned short* __restrict__ Bw,
    const float* __restrict__ bias0, const float* __restrict__ bias1,
    unsigned short* __restrict__ Out0, unsigned short* __restrict__ Out1,
    float* __restrict__ OutF,
    float* __restrict__ sum1, float* __restrict__ sum2)
{
  constexpr int GN  = (MODE == 0) ? 8 : 4;
  constexpr int NWG = (MODE == 0) ? 8192 : 4096;
  __shared__ __align__(16) unsigned short SM[6 * 128 * 32];

  int raw = blockIdx.x;
  int lid = (raw & 7) * (NWG / 8) + (raw >> 3);
  int tileN = lid & (GN - 1);
  int tileM = lid / GN;
  int tm128 = tileM * 128;
  int b512 = (tileM >> 7) * 512;
  int tid = threadIdx.x;
  int wave = tid >> 6, lane = tid & 63;
  int wr = (wave >> 1) * 64, wc = (wave & 1) * 64;
  int r15 = lane & 15, kcg = lane >> 4;

  floatx4 acc[4][4];
  floatx4 zz = {0.f, 0.f, 0.f, 0.f};
  #pragma unroll
  for (int m = 0; m < 4; m++)
    #pragma unroll
    for (int n = 0; n < 4; n++) acc[m][n] = zz;

  const unsigned short* Arow = A + (size_t)tm128 * 512;
  const unsigned short* Brow = Bw + (size_t)(tileN * 128) * 512;

  auto stage = [&](int kt, int s) {
    int k0 = kt * 32;
    unsigned short* As = SM + s * 4096;
    unsigned short* Bs = SM + (3 + s) * 4096;
    #pragma unroll
    for (int i = 0; i < 2; i++) {
      int idx = i * 256 + tid;
      int row = idx >> 2;
      int c = (idx & 3) ^ ((row >> 1) & 3);
      stage16(&Arow[(size_t)row * 512 + k0 + c * 8],
              &As[(i * 256 + wave * 64) * 8]);
    }
    #pragma unroll
    for (int i = 0; i < 2; i++) {
      int idx = i * 256 + tid;
      int row = idx >> 2;
      int c = (idx & 3) ^ ((row >> 1) & 3);
      stage16(&Brow[(size_t)row * 512 + k0 + c * 8],
              &Bs[(i * 256 + wave * 64) * 8]);
    }
  };

  stage(0, 0);
  stage(1, 1);
  #pragma unroll
  for (int kt = 0; kt < 16; kt++) {
    int s = kt % 3;
    __builtin_amdgcn_sched_barrier(0);
    if (kt < 15) asm volatile("s_waitcnt vmcnt(4) lgkmcnt(0)\n\ts_barrier" ::: "memory");
    else         asm volatile("s_waitcnt vmcnt(0) lgkmcnt(0)\n\ts_barrier" ::: "memory");
    __builtin_amdgcn_sched_barrier(0);
    if (kt + 2 < 16) stage(kt + 2, (kt + 2) % 3);
    const unsigned short* As = SM + s * 4096;
    const unsigned short* Bs = SM + (3 + s) * 4096;
    short8 af[4], bfv[4];
    #pragma unroll
    for (int m = 0; m < 4; m++) {
      int R = wr + m * 16 + r15;
      af[m] = *reinterpret_cast<const short8*>(&As[R * 32 + (kcg ^ ((R >> 1) & 3)) * 8]);
    }
    #pragma unroll
    for (int n = 0; n < 4; n++) {
      int R = wc + n * 16 + r15;
      bfv[n] = *reinterpret_cast<const short8*>(&Bs[R * 32 + (kcg ^ ((R >> 1) & 3)) * 8]);
    }
    #pragma unroll
    for (int m = 0; m < 4; m++)
      #pragma unroll
      for (int n = 0; n < 4; n++)
        acc[m][n] = __builtin_amdgcn_mfma_f32_16x16x32_bf16(af[m], bfv[n], acc[m][n], 0, 0, 0);
  }

  __syncthreads();

  if constexpr (MODE == 2) {
    int baseM = tm128 + wr + (lane >> 4) * 4;
    #pragma unroll
    for (int n = 0; n < 4; n++) {
      int gcol = tileN * 128 + wc + n * 16 + r15;
      #pragma unroll
      for (int m = 0; m < 4; m++) {
        int rowb = baseM + m * 16;
        #pragma unroll
        for (int j = 0; j < 4; j++) {
          float v = geluf(acc[m][n][j] + bias0[gcol]);
          OutF[(size_t)(rowb + j) * 512 + gcol] = v;
        }
      }
    }
  } else {
    unsigned short* C = SM;
    int baseR = wr + (lane >> 4) * 4;
    #pragma unroll
    for (int n = 0; n < 4; n++) {
      int lcol = wc + n * 16 + r15;
      int gcol = tileN * 128 + lcol;
      float s1 = 0.f, s2 = 0.f;
      #pragma unroll
      for (int m = 0; m < 4; m++) {
        #pragma unroll
        for (int j = 0; j < 4; j++) {
          int lrow = baseR + m * 16 + j;
          float v = acc[m][n][j];
          if constexpr (MODE == 0) {
            if (tileN < 4) {
              v = geluf(v + bias0[gcol]);
            } else {
              v += bias1[gcol - 512];
              s1 += v; s2 += v * v;
            }
          } else {
            v += bias0[gcol];
            s1 += v; s2 += v * v;
          }
          C[lrow * 128 + (lcol ^ (((lrow >> 2) & 3) << 4))] = f2bf(v);
        }
      }
      bool doStats = (MODE == 1) || (tileN >= 4);
      if (doStats) {
        s1 += __shfl_xor(s1, 16); s1 += __shfl_xor(s1, 32);
        s2 += __shfl_xor(s2, 16); s2 += __shfl_xor(s2, 32);
        if (lane < 16) {
          int c = (MODE == 0) ? (gcol - 512) : gcol;
          atomicAdd(&sum1[b512 + c], s1);
          atomicAdd(&sum2[b512 + c], s2);
        }
      }
    }
    __syncthreads();
    unsigned short* Og;
    int colbase;
    if constexpr (MODE == 0) {
      if (tileN < 4) { Og = Out0; colbase = tileN * 128; }
      else           { Og = Out1; colbase = (tileN - 4) * 128; }
    } else {
      Og = Out0; colbase = tileN * 128;
    }
    #pragma unroll
    for (int t = 0; t < 8; t++) {
      int cid = t * 256 + tid;
      int row = cid >> 4, cc = cid & 15;
      uint4 d = *reinterpret_cast<const uint4*>(&C[row * 128 + ((cc * 8) ^ (((row >> 2) & 3) << 4))]);
      *reinterpret_cast<uint4*>(&Og[(size_t)(tm128 + row) * 512 + colbase + cc * 8]) = d;
    }
  }
}

extern "C" void kernel_launch(void* const* d_in, const int* in_sizes, int n_in,
                              void* d_out, int out_size, void* d_ws, size_t ws_size,
                              hipStream_t stream)
{
  const float* x   = (const float*)d_in[0];
  const float* l   = (const float*)d_in[1];
  const float* Wv  = (const float*)d_in[3];
  const float* bv  = (const float*)d_in[4];
  const float* Wq  = (const float*)d_in[5];
  const float* bq  = (const float*)d_in[6];
  const float* Wk  = (const float*)d_in[7];
  const float* bk  = (const float*)d_in[8];
  const float* Wva = (const float*)d_in[9];
  const float* bva = (const float*)d_in[10];
  const float* Ww  = (const float*)d_in[11];
  const float* bw  = (const float*)d_in[12];
  const float* Wm  = (const float*)d_in[13];
  const float* bm  = (const float*)d_in[14];

  char* w = (char*)d_ws;
  size_t o = 0;
  auto alloc = [&](size_t bytes) { size_t r = o; o += (bytes + 255) & ~(size_t)255; return r; };
  size_t WCATT = alloc(1024 * 512 * 2);
  size_t WWT   = alloc(512 * 512 * 2);
  size_t WMT   = alloc(512 * 512 * 2);
  size_t KRAW  = alloc((size_t)NB * NLANG * 512 * 4);
  size_t VB    = alloc((size_t)NB * NLANG * 512 * 2);
  size_t KP    = alloc((size_t)NB * NLANG * 512 * 2);
  size_t OFFW  = alloc((size_t)NB * NHEADS * NLANG * 4);
  size_t STATS = alloc((size_t)4 * NB * 512 * 4);
  size_t LMA   = alloc((size_t)NB * 512 * 4);
  size_t LMB   = alloc((size_t)NB * 512 * 4);
  size_t XB    = alloc((size_t)MTOT * 512 * 2);  // xb; reused as mm after gemm0
  size_t VIS   = alloc((size_t)MTOT * 512 * 2);
  size_t QBUF  = alloc((size_t)MTOT * 512 * 2);
  size_t YBUF  = alloc((size_t)MTOT * 512 * 2);

  float* qsum = (float*)(w + STATS);
  float* qsq  = qsum + NB * 512;
  float* ysum = qsq + NB * 512;
  float* ysq  = ysum + NB * 512;

  hipMemsetAsync(w + STATS, 0, (size_t)4 * NB * 512 * 4, stream);
  prep_w<<<4096, 256, 0, stream>>>(Wv, Wq, Ww, Wm,
      (unsigned short*)(w + WCATT), (unsigned short*)(w + WWT), (unsigned short*)(w + WMT));
  xcvt<<<32768, 256, 0, stream>>>(x, (unsigned short*)(w + XB));
  prep_kv<<<640, 256, 0, stream>>>(l, Wk, bk, Wva, bva,
      (float*)(w + KRAW), (unsigned short*)(w + VB));
  gemm8<<<2048, 512, 0, stream>>>((const unsigned short*)(w + XB),
      (const unsigned short*)(w + WCATT), bv, bq,
      (unsigned short*)(w + VIS), (unsigned short*)(w + QBUF), qsum, qsq);
  kprep<<<160, 64, 0, stream>>>(qsum, qsq, (const float*)(w + KRAW),
      (unsigned short*)(w + KP), (float*)(w + OFFW));
  attn_k<<<4096, 256, 0, stream>>>((const unsigned short*)(w + KP),
      (const unsigned short*)(w + VB), (const float*)(w + OFFW),
      (unsigned short*)(w + QBUF));
  gemm_k<1><<<4096, 256, 0, stream>>>((const unsigned short*)(w + QBUF),
      (const unsigned short*)(w + WWT), bw, nullptr,
      (unsigned short*)(w + YBUF), nullptr, nullptr, ysum, ysq);
  lmk<<<16, 256, 0, stream>>>(ysum, ysq, (float*)(w + LMA), (float*)(w + LMB));
  mmk<<<32768, 256, 0, stream>>>((const unsigned short*)(w + YBUF),
      (const unsigned short*)(w + VIS), (const float*)(w + LMA), (const float*)(w + LMB),
      (unsigned short*)(w + XB));
  gemm_k<2><<<4096, 256, 0, stream>>>((const unsigned short*)(w + XB),
      (const unsigned short*)(w + WMT), bm, nullptr,
      nullptr, nullptr, (float*)d_out, nullptr, nullptr);
}

// Round 14
// 861.006 us; speedup vs baseline: 1.1853x; 1.1853x over previous
//
#include <hip/hip_runtime.h>

#define HWN 16384
#define DMODEL 512
#define NLANG 20
#define LCH 768
#define NB 8
#define MTOT (NB*HWN)
#define NHEADS 8

typedef float floatx4 __attribute__((ext_vector_type(4)));
typedef short short8 __attribute__((ext_vector_type(8)));

__device__ __forceinline__ float bflo(unsigned u){ return __uint_as_float(u << 16); }
__device__ __forceinline__ float bfhi(unsigned u){ return __uint_as_float(u & 0xffff0000u); }
__device__ __forceinline__ unsigned short f2bf(float f){
  unsigned u = __float_as_uint(f);
  u += 0x7fffu + ((u >> 16) & 1u);
  return (unsigned short)(u >> 16);
}
__device__ __forceinline__ unsigned pack2(float a, float b){
  return (unsigned)f2bf(a) | ((unsigned)f2bf(b) << 16);
}
// tanh-form GELU (max |err| vs exact ~5e-4)
__device__ __forceinline__ float geluf(float v){
  float t = v * v;
  float u2 = v * fmaf(t, -0.0713548162f, -1.5957691216f); // -2*u
  float e = __expf(u2);
  return v * __builtin_amdgcn_rcpf(1.0f + e);
}
__device__ __forceinline__ void stage16(const void* g, void* l){
  __builtin_amdgcn_global_load_lds(
      (const __attribute__((address_space(1))) void*)g,
      (__attribute__((address_space(3))) void*)l, 16, 0, 0);
}
// transpose-within-row chunk permutation: chunk c (0..63) -> slot ((c&7)<<3)|(c>>3)
__device__ __forceinline__ int tslot(int c){ return ((c & 7) << 3) | (c >> 3); }

// ---------------- prep: transpose weights to [N][K] bf16 ----------------
__global__ void prep_w(const float* __restrict__ Wv, const float* __restrict__ Wq,
                       const float* __restrict__ Wm,
                       unsigned short* __restrict__ wcatT, unsigned short* __restrict__ wmT)
{
  int i = blockIdx.x * 256 + threadIdx.x;
  if (i < 1024 * 512) {
    int n = i >> 9, k = i & 511;
    float v = (n < 512) ? Wv[k * 512 + n] : Wq[k * 512 + (n - 512)];
    wcatT[i] = f2bf(v);
  } else {
    int j = i - 1024 * 512;
    int n = j >> 9, k = j & 511;
    wmT[j] = f2bf(Wm[k * 512 + n]);
  }
}

// ---------------- x fp32 -> bf16 ----------------
__global__ void xcvt(const float* __restrict__ x, unsigned short* __restrict__ xb)
{
  size_t i = ((size_t)blockIdx.x * 256 + threadIdx.x) * 8;
  float4 a = *reinterpret_cast<const float4*>(&x[i]);
  float4 b = *reinterpret_cast<const float4*>(&x[i + 4]);
  uint4 d;
  d.x = pack2(a.x, a.y); d.y = pack2(a.z, a.w);
  d.z = pack2(b.x, b.y); d.w = pack2(b.z, b.w);
  *reinterpret_cast<uint4*>(&xb[i]) = d;
}

// ---------------- mm = vis * (y*a + b) ----------------
__global__ void mmk(const unsigned short* __restrict__ y, const unsigned short* __restrict__ vis,
                    const float* __restrict__ lma, const float* __restrict__ lmb,
                    unsigned short* __restrict__ mm)
{
  size_t i = ((size_t)blockIdx.x * 256 + threadIdx.x) * 8;
  int c = (int)(i & 511);
  int b = (int)(i >> 23);
  uint4 yv = *reinterpret_cast<const uint4*>(&y[i]);
  uint4 vv = *reinterpret_cast<const uint4*>(&vis[i]);
  const float* Ap = &lma[b * 512 + c];
  const float* Bp = &lmb[b * 512 + c];
  float4 a0 = *reinterpret_cast<const float4*>(Ap);
  float4 a1 = *reinterpret_cast<const float4*>(Ap + 4);
  float4 b0 = *reinterpret_cast<const float4*>(Bp);
  float4 b1 = *reinterpret_cast<const float4*>(Bp + 4);
  float m0 = bflo(vv.x) * (bflo(yv.x) * a0.x + b0.x);
  float m1 = bfhi(vv.x) * (bfhi(yv.x) * a0.y + b0.y);
  float m2 = bflo(vv.y) * (bflo(yv.y) * a0.z + b0.z);
  float m3 = bfhi(vv.y) * (bfhi(yv.y) * a0.w + b0.w);
  float m4 = bflo(vv.z) * (bflo(yv.z) * a1.x + b1.x);
  float m5 = bfhi(vv.z) * (bfhi(yv.z) * a1.y + b1.y);
  float m6 = bflo(vv.w) * (bflo(yv.w) * a1.z + b1.z);
  float m7 = bfhi(vv.w) * (bfhi(yv.w) * a1.w + b1.w);
  uint4 d;
  d.x = pack2(m0, m1); d.y = pack2(m2, m3);
  d.z = pack2(m4, m5); d.w = pack2(m6, m7);
  *reinterpret_cast<uint4*>(&mm[i]) = d;
}

// ---------------- prep: k = l@Wk+bk (fp32), v = l@Wval+bval (bf16, LINEAR layout) ----------------
__global__ void prep_kv(const float* __restrict__ l, const float* __restrict__ Wk,
                        const float* __restrict__ bk, const float* __restrict__ Wval,
                        const float* __restrict__ bval,
                        float* __restrict__ kraw, unsigned short* __restrict__ vb)
{
  int i = blockIdx.x * 256 + threadIdx.x;
  int which = i / (NB * NLANG * 512);
  int j = i - which * (NB * NLANG * 512);
  int bt = j >> 9;
  int c = j & 511;
  const float* W = which ? Wval : Wk;
  float acc = which ? bval[c] : bk[c];
  const float* lr = l + (size_t)bt * LCH;
  for (int p = 0; p < LCH; p++) acc = fmaf(lr[p], W[p * 512 + c], acc);
  if (which) vb[j] = f2bf(acc);
  else       kraw[j] = acc;
}

// ---------------- W2~T[b][n][h*32+t] = sum_d v[b][t][h*64+d] * Ww[h*64+d][n]  (bf16 out) ------
__global__ void w2prep(const unsigned short* __restrict__ vb, const float* __restrict__ Ww,
                       unsigned short* __restrict__ w2t)
{
  int i = blockIdx.x * 256 + threadIdx.x;   // NB*512*256 = 1M
  int k = i & 255;
  int n = (i >> 8) & 511;
  int b = i >> 17;
  int t = k & 31, h = k >> 5;
  float acc = 0.f;
  if (t < NLANG) {
    const unsigned short* vr = &vb[(size_t)(b * NLANG + t) * 512 + h * 64];
    const float* wr = &Ww[(size_t)(h * 64) * 512 + n];
    #pragma unroll 8
    for (int d = 0; d < 64; d++)
      acc = fmaf(__uint_as_float((unsigned)vr[d] << 16), wr[d * 512], acc);
  }
  w2t[(size_t)(b * 512 + n) * 256 + k] = f2bf(acc);
}

// ---------------- fold q-instance-norm into k' (tslot layout) ----------------
__global__ void kprep(const float* __restrict__ qsum, const float* __restrict__ qsq,
                      const float* __restrict__ kraw, unsigned short* __restrict__ kp,
                      float* __restrict__ offG)
{
  int blk = blockIdx.x; int b = blk / NLANG, t = blk - b * NLANG;
  int lane = threadIdx.x;
  float offp = 0.f;
  float vals[8];
  #pragma unroll
  for (int e = 0; e < 8; e++) {
    int c = lane * 8 + e;
    float mean = qsum[b * 512 + c] * (1.f / 16384.f);
    float var  = qsq[b * 512 + c] * (1.f / 16384.f) - mean * mean;
    float inv  = rsqrtf(var + 1e-5f);
    float a = inv * 0.044194173824159216f;
    float kv = kraw[((size_t)(b * NLANG + t)) * 512 + c];
    vals[e] = kv * a;
    offp += (-mean * a) * kv;
  }
  unsigned u0 = pack2(vals[0], vals[1]);
  unsigned u1 = pack2(vals[2], vals[3]);
  unsigned u2 = pack2(vals[4], vals[5]);
  unsigned u3 = pack2(vals[6], vals[7]);
  uint4 uu = make_uint4(u0, u1, u2, u3);
  *reinterpret_cast<uint4*>(&kp[((size_t)(b * NLANG + t)) * 512 + tslot(lane) * 8]) = uu;
  offp += __shfl_xor(offp, 1);
  offp += __shfl_xor(offp, 2);
  offp += __shfl_xor(offp, 4);
  if ((lane & 7) == 0) offG[(b * 8 + (lane >> 3)) * NLANG + t] = offp;
}

// ---------------- lang-norm coefficients ----------------
__global__ void lmk(const float* __restrict__ ysum, const float* __restrict__ ysq,
                    float* __restrict__ lma, float* __restrict__ lmb)
{
  int i = blockIdx.x * 256 + threadIdx.x;
  if (i < NB * 512) {
    float mean = ysum[i] * (1.f / 16384.f);
    float var  = ysq[i] * (1.f / 16384.f) - mean * mean;
    float inv  = rsqrtf(var + 1e-5f);
    lma[i] = inv; lmb[i] = -mean * inv;
  }
}

// ---------------- attention scores only: P~[r][h*32+t] = softmax_t(q_h . k'_h) (bf16) --------
__global__ __launch_bounds__(256, 3) void attn_k(
    const unsigned short* __restrict__ kp, const float* __restrict__ offG,
    const unsigned short* __restrict__ qb, unsigned short* __restrict__ pb)
{
  __shared__ __align__(16) unsigned short kps[NLANG * 512];
  __shared__ __align__(16) unsigned short qs[32 * 512];
  __shared__ float offs[NHEADS * NLANG];
  int tid = threadIdx.x, bid = blockIdx.x;
  int b = bid >> 9;
  int row0 = (bid & 511) * 32;
  size_t base = (size_t)b * (NLANG * 512);
  const uint4* kg = reinterpret_cast<const uint4*>(kp + base);
  uint4* kl = reinterpret_cast<uint4*>(kps);
  #pragma unroll
  for (int i = 0; i < 5; i++) { int o = i * 256 + tid; kl[o] = kg[o]; }
  if (tid < NHEADS * NLANG) offs[tid] = offG[b * (NHEADS * NLANG) + tid];

  size_t grow0 = (size_t)b * HWN + row0;
  // q: coalesced global load -> transposed LDS slots
  #pragma unroll
  for (int i = 0; i < 8; i++) {
    int g = i * 256 + tid;
    int row = g >> 6, c = g & 63;
    uint4 d = *reinterpret_cast<const uint4*>(&qb[(grow0 + row) * 512 + c * 8]);
    *reinterpret_cast<uint4*>(&qs[row * 512 + tslot(c) * 8]) = d;
  }
  __syncthreads();

  int r = tid >> 3, h = tid & 7;
  float sim[NLANG];
  #pragma unroll
  for (int t = 0; t < NLANG; t++) sim[t] = offs[h * NLANG + t];
  #pragma unroll
  for (int j = 0; j < 8; j++) {
    uint4 qv = *reinterpret_cast<const uint4*>(&qs[r * 512 + (j * 8 + h) * 8]);
    float q0 = bflo(qv.x), q1 = bfhi(qv.x), q2 = bflo(qv.y), q3 = bfhi(qv.y);
    float q4 = bflo(qv.z), q5 = bfhi(qv.z), q6 = bflo(qv.w), q7 = bfhi(qv.w);
    #pragma unroll
    for (int t = 0; t < NLANG; t++) {
      uint4 kv = *reinterpret_cast<const uint4*>(&kps[t * 512 + (j * 8 + h) * 8]);
      float a = sim[t];
      a = fmaf(q0, bflo(kv.x), a); a = fmaf(q1, bfhi(kv.x), a);
      a = fmaf(q2, bflo(kv.y), a); a = fmaf(q3, bfhi(kv.y), a);
      a = fmaf(q4, bflo(kv.z), a); a = fmaf(q5, bfhi(kv.z), a);
      a = fmaf(q6, bflo(kv.w), a); a = fmaf(q7, bfhi(kv.w), a);
      sim[t] = a;
    }
  }
  float mx = sim[0];
  #pragma unroll
  for (int t = 1; t < NLANG; t++) mx = fmaxf(mx, sim[t]);
  float s = 0.f;
  #pragma unroll
  for (int t = 0; t < NLANG; t++) { float e = __expf(sim[t] - mx); sim[t] = e; s += e; }
  float invs = 1.f / s;
  #pragma unroll
  for (int t = 0; t < NLANG; t++) sim[t] *= invs;

  // write P~ row slice: 20 bf16 + 12 zeros at [grow][h*32 .. h*32+31]
  unsigned uu[16];
  #pragma unroll
  for (int j = 0; j < 10; j++) uu[j] = pack2(sim[2 * j], sim[2 * j + 1]);
  #pragma unroll
  for (int j = 10; j < 16; j++) uu[j] = 0u;
  size_t prow = (grow0 + r) * 256 + h * 32;
  #pragma unroll
  for (int j = 0; j < 4; j++)
    *reinterpret_cast<uint4*>(&pb[prow + j * 8]) =
        make_uint4(uu[4 * j], uu[4 * j + 1], uu[4 * j + 2], uu[4 * j + 3]);
}

// ---------------- GEMM: 128x128 tile, BK=32, 3-buf dist-2, counted vmcnt+lgkm (r9 proven) ----
// KD = K dimension (A and B row stride). MODE 0: KD=512, N=1024 (vis gelu | q + stats).
// MODE 1: KD=256, A=P~, B=W2~T per batch; y = acc + bw -> bf16 + stats.
// MODE 2: KD=512; gelu(acc+bm) -> fp32 out.
template<int MODE, int KD>
__global__ __launch_bounds__(256) void gemm_k(
    const unsigned short* __restrict__ A,
    const unsigned short* __restrict__ Bw,
    const float* __restrict__ bias0, const float* __restrict__ bias1,
    unsigned short* __restrict__ Out0, unsigned short* __restrict__ Out1,
    float* __restrict__ OutF,
    float* __restrict__ sum1, float* __restrict__ sum2)
{
  constexpr int GN  = (MODE == 0) ? 8 : 4;
  constexpr int NWG = (MODE == 0) ? 8192 : 4096;
  constexpr int KT  = KD / 32;
  __shared__ __align__(16) unsigned short SM[6 * 128 * 32];

  int raw = blockIdx.x;
  int lid = (raw & 7) * (NWG / 8) + (raw >> 3);
  int tileN = lid & (GN - 1);
  int tileM = lid / GN;
  int tm128 = tileM * 128;
  int b512 = (tileM >> 7) * 512;
  int tid = threadIdx.x;
  int wave = tid >> 6, lane = tid & 63;
  int wr = (wave >> 1) * 64, wc = (wave & 1) * 64;
  int r15 = lane & 15, kcg = lane >> 4;

  floatx4 acc[4][4];
  floatx4 zz = {0.f, 0.f, 0.f, 0.f};
  #pragma unroll
  for (int m = 0; m < 4; m++)
    #pragma unroll
    for (int n = 0; n < 4; n++) acc[m][n] = zz;

  const unsigned short* Arow = A + (size_t)tm128 * KD;
  const unsigned short* Brow = Bw +
      ((MODE == 1) ? (size_t)(tileM >> 7) * 512 * KD : (size_t)0) +
      (size_t)(tileN * 128) * KD;

  auto stage = [&](int kt, int s) {
    int k0 = kt * 32;
    unsigned short* As = SM + s * 4096;
    unsigned short* Bs = SM + (3 + s) * 4096;
    #pragma unroll
    for (int i = 0; i < 2; i++) {
      int idx = i * 256 + tid;
      int row = idx >> 2;
      int c = (idx & 3) ^ ((row >> 1) & 3);
      stage16(&Arow[(size_t)row * KD + k0 + c * 8],
              &As[(i * 256 + wave * 64) * 8]);
    }
    #pragma unroll
    for (int i = 0; i < 2; i++) {
      int idx = i * 256 + tid;
      int row = idx >> 2;
      int c = (idx & 3) ^ ((row >> 1) & 3);
      stage16(&Brow[(size_t)row * KD + k0 + c * 8],
              &Bs[(i * 256 + wave * 64) * 8]);
    }
  };

  stage(0, 0);
  stage(1, 1);
  #pragma unroll
  for (int kt = 0; kt < KT; kt++) {
    int s = kt % 3;
    __builtin_amdgcn_sched_barrier(0);
    if (kt < KT - 1) asm volatile("s_waitcnt vmcnt(4) lgkmcnt(0)\n\ts_barrier" ::: "memory");
    else             asm volatile("s_waitcnt vmcnt(0) lgkmcnt(0)\n\ts_barrier" ::: "memory");
    __builtin_amdgcn_sched_barrier(0);
    if (kt + 2 < KT) stage(kt + 2, (kt + 2) % 3);
    const unsigned short* As = SM + s * 4096;
    const unsigned short* Bs = SM + (3 + s) * 4096;
    short8 af[4], bfv[4];
    #pragma unroll
    for (int m = 0; m < 4; m++) {
      int R = wr + m * 16 + r15;
      af[m] = *reinterpret_cast<const short8*>(&As[R * 32 + (kcg ^ ((R >> 1) & 3)) * 8]);
    }
    #pragma unroll
    for (int n = 0; n < 4; n++) {
      int R = wc + n * 16 + r15;
      bfv[n] = *reinterpret_cast<const short8*>(&Bs[R * 32 + (kcg ^ ((R >> 1) & 3)) * 8]);
    }
    #pragma unroll
    for (int m = 0; m < 4; m++)
      #pragma unroll
      for (int n = 0; n < 4; n++)
        acc[m][n] = __builtin_amdgcn_mfma_f32_16x16x32_bf16(af[m], bfv[n], acc[m][n], 0, 0, 0);
  }

  __syncthreads();

  if constexpr (MODE == 2) {
    int baseM = tm128 + wr + (lane >> 4) * 4;
    #pragma unroll
    for (int n = 0; n < 4; n++) {
      int gcol = tileN * 128 + wc + n * 16 + r15;
      #pragma unroll
      for (int m = 0; m < 4; m++) {
        int rowb = baseM + m * 16;
        #pragma unroll
        for (int j = 0; j < 4; j++) {
          float v = geluf(acc[m][n][j] + bias0[gcol]);
          OutF[(size_t)(rowb + j) * 512 + gcol] = v;
        }
      }
    }
  } else {
    unsigned short* C = SM;
    int baseR = wr + (lane >> 4) * 4;
    #pragma unroll
    for (int n = 0; n < 4; n++) {
      int lcol = wc + n * 16 + r15;
      int gcol = tileN * 128 + lcol;
      float s1 = 0.f, s2 = 0.f;
      #pragma unroll
      for (int m = 0; m < 4; m++) {
        #pragma unroll
        for (int j = 0; j < 4; j++) {
          int lrow = baseR + m * 16 + j;
          float v = acc[m][n][j];
          if constexpr (MODE == 0) {
            if (tileN < 4) {
              v = geluf(v + bias0[gcol]);
            } else {
              v += bias1[gcol - 512];
              s1 += v; s2 += v * v;
            }
          } else {
            v += bias0[gcol];
            s1 += v; s2 += v * v;
          }
          C[lrow * 128 + (lcol ^ (((lrow >> 2) & 3) << 4))] = f2bf(v);
        }
      }
      bool doStats = (MODE == 1) || (tileN >= 4);
      if (doStats) {
        s1 += __shfl_xor(s1, 16); s1 += __shfl_xor(s1, 32);
        s2 += __shfl_xor(s2, 16); s2 += __shfl_xor(s2, 32);
        if (lane < 16) {
          int c = (MODE == 0) ? (gcol - 512) : gcol;
          atomicAdd(&sum1[b512 + c], s1);
          atomicAdd(&sum2[b512 + c], s2);
        }
      }
    }
    __syncthreads();
    unsigned short* Og;
    int colbase;
    if constexpr (MODE == 0) {
      if (tileN < 4) { Og = Out0; colbase = tileN * 128; }
      else           { Og = Out1; colbase = (tileN - 4) * 128; }
    } else {
      Og = Out0; colbase = tileN * 128;
    }
    #pragma unroll
    for (int t = 0; t < 8; t++) {
      int cid = t * 256 + tid;
      int row = cid >> 4, cc = cid & 15;
      uint4 d = *reinterpret_cast<const uint4*>(&C[row * 128 + ((cc * 8) ^ (((row >> 2) & 3) << 4))]);
      *reinterpret_cast<uint4*>(&Og[(size_t)(tm128 + row) * 512 + colbase + cc * 8]) = d;
    }
  }
}

extern "C" void kernel_launch(void* const* d_in, const int* in_sizes, int n_in,
                              void* d_out, int out_size, void* d_ws, size_t ws_size,
                              hipStream_t stream)
{
  const float* x   = (const float*)d_in[0];
  const float* l   = (const float*)d_in[1];
  const float* Wv  = (const float*)d_in[3];
  const float* bv  = (const float*)d_in[4];
  const float* Wq  = (const float*)d_in[5];
  const float* bq  = (const float*)d_in[6];
  const float* Wk  = (const float*)d_in[7];
  const float* bk  = (const float*)d_in[8];
  const float* Wva = (const float*)d_in[9];
  const float* bva = (const float*)d_in[10];
  const float* Ww  = (const float*)d_in[11];
  const float* bw  = (const float*)d_in[12];
  const float* Wm  = (const float*)d_in[13];
  const float* bm  = (const float*)d_in[14];

  char* w = (char*)d_ws;
  size_t o = 0;
  auto alloc = [&](size_t bytes) { size_t r = o; o += (bytes + 255) & ~(size_t)255; return r; };
  size_t WCATT = alloc(1024 * 512 * 2);
  size_t WMT   = alloc(512 * 512 * 2);
  size_t W2T   = alloc((size_t)NB * 512 * 256 * 2);
  size_t KRAW  = alloc((size_t)NB * NLANG * 512 * 4);
  size_t VB    = alloc((size_t)NB * NLANG * 512 * 2);
  size_t KP    = alloc((size_t)NB * NLANG * 512 * 2);
  size_t OFFW  = alloc((size_t)NB * NHEADS * NLANG * 4);
  size_t STATS = alloc((size_t)4 * NB * 512 * 4);
  size_t LMA   = alloc((size_t)NB * 512 * 4);
  size_t LMB   = alloc((size_t)NB * 512 * 4);
  size_t XB    = alloc((size_t)MTOT * 512 * 2);  // xb; reused as mm after gemm0
  size_t VIS   = alloc((size_t)MTOT * 512 * 2);
  size_t QBUF  = alloc((size_t)MTOT * 512 * 2);
  size_t PB    = alloc((size_t)MTOT * 256 * 2);  // P~ [M][256] bf16
  size_t YBUF  = alloc((size_t)MTOT * 512 * 2);

  float* qsum = (float*)(w + STATS);
  float* qsq  = qsum + NB * 512;
  float* ysum = qsq + NB * 512;
  float* ysq  = ysum + NB * 512;

  hipMemsetAsync(w + STATS, 0, (size_t)4 * NB * 512 * 4, stream);
  prep_w<<<3072, 256, 0, stream>>>(Wv, Wq, Wm,
      (unsigned short*)(w + WCATT), (unsigned short*)(w + WMT));
  xcvt<<<32768, 256, 0, stream>>>(x, (unsigned short*)(w + XB));
  prep_kv<<<640, 256, 0, stream>>>(l, Wk, bk, Wva, bva,
      (float*)(w + KRAW), (unsigned short*)(w + VB));
  w2prep<<<4096, 256, 0, stream>>>((const unsigned short*)(w + VB), Ww,
      (unsigned short*)(w + W2T));
  gemm_k<0, 512><<<8192, 256, 0, stream>>>((const unsigned short*)(w + XB),
      (const unsigned short*)(w + WCATT), bv, bq,
      (unsigned short*)(w + VIS), (unsigned short*)(w + QBUF), nullptr, qsum, qsq);
  kprep<<<160, 64, 0, stream>>>(qsum, qsq, (const float*)(w + KRAW),
      (unsigned short*)(w + KP), (float*)(w + OFFW));
  attn_k<<<4096, 256, 0, stream>>>((const unsigned short*)(w + KP),
      (const float*)(w + OFFW), (const unsigned short*)(w + QBUF),
      (unsigned short*)(w + PB));
  gemm_k<1, 256><<<4096, 256, 0, stream>>>((const unsigned short*)(w + PB),
      (const unsigned short*)(w + W2T), bw, nullptr,
      (unsigned short*)(w + YBUF), nullptr, nullptr, ysum, ysq);
  lmk<<<16, 256, 0, stream>>>(ysum, ysq, (float*)(w + LMA), (float*)(w + LMB));
  mmk<<<32768, 256, 0, stream>>>((const unsigned short*)(w + YBUF),
      (const unsigned short*)(w + VIS), (const float*)(w + LMA), (const float*)(w + LMB),
      (unsigned short*)(w + XB));
  gemm_k<2, 512><<<4096, 256, 0, stream>>>((const unsigned short*)(w + XB),
      (const unsigned short*)(w + WMT), bm, nullptr,
      nullptr, nullptr, (float*)d_out, nullptr, nullptr);
}

// Round 15
// 801.600 us; speedup vs baseline: 1.2731x; 1.0741x over previous
//
#include <hip/hip_runtime.h>

#define HWN 16384
#define DMODEL 512
#define NLANG 20
#define LCH 768
#define NB 8
#define MTOT (NB*HWN)
#define NHEADS 8

typedef float floatx4 __attribute__((ext_vector_type(4)));
typedef short short8 __attribute__((ext_vector_type(8)));

__device__ __forceinline__ float bflo(unsigned u){ return __uint_as_float(u << 16); }
__device__ __forceinline__ float bfhi(unsigned u){ return __uint_as_float(u & 0xffff0000u); }
__device__ __forceinline__ unsigned short f2bf(float f){
  unsigned u = __float_as_uint(f);
  u += 0x7fffu + ((u >> 16) & 1u);
  return (unsigned short)(u >> 16);
}
__device__ __forceinline__ unsigned pack2(float a, float b){
  return (unsigned)f2bf(a) | ((unsigned)f2bf(b) << 16);
}
// tanh-form GELU (max |err| vs exact ~5e-4)
__device__ __forceinline__ float geluf(float v){
  float t = v * v;
  float u2 = v * fmaf(t, -0.0713548162f, -1.5957691216f); // -2*u
  float e = __expf(u2);
  return v * __builtin_amdgcn_rcpf(1.0f + e);
}
__device__ __forceinline__ void stage16(const void* g, void* l){
  __builtin_amdgcn_global_load_lds(
      (const __attribute__((address_space(1))) void*)g,
      (__attribute__((address_space(3))) void*)l, 16, 0, 0);
}
// transpose-within-row chunk permutation: chunk c (0..63) -> slot ((c&7)<<3)|(c>>3)
__device__ __forceinline__ int tslot(int c){ return ((c & 7) << 3) | (c >> 3); }

// DPP quad_perm move (VALU pipe, 4-lane groups)
template<int CTRL>
__device__ __forceinline__ float dppf(float x){
  return __int_as_float(__builtin_amdgcn_mov_dpp(__float_as_int(x), CTRL, 0xf, 0xf, true));
}
// 4x4 transpose within 4-lane quads: in v[j] = M[j][lane&3], out v[j] = M[lane&3][j].
__device__ __forceinline__ void quadT(float v[4], int lane){
  float t0 = dppf<0xB1>(v[1]), t1 = dppf<0xB1>(v[0]);
  float t2 = dppf<0xB1>(v[3]), t3 = dppf<0xB1>(v[2]);
  int p0 = lane & 1;
  float w0 = (p0 == 0) ? v[0] : t0;
  float w1 = (p0 == 1) ? v[1] : t1;
  float w2 = (p0 == 0) ? v[2] : t2;
  float w3 = (p0 == 1) ? v[3] : t3;
  float s0 = dppf<0x4E>(w2), s1 = dppf<0x4E>(w3);
  float s2 = dppf<0x4E>(w0), s3 = dppf<0x4E>(w1);
  int p1 = lane & 2;
  v[0] = (p1 == 0) ? w0 : s0;
  v[1] = (p1 == 0) ? w1 : s1;
  v[2] = (p1 == 2) ? w2 : s2;
  v[3] = (p1 == 2) ? w3 : s3;
}

// ---------------- prep: transpose weights to [N][K] bf16 ----------------
__global__ void prep_w(const float* __restrict__ Wv, const float* __restrict__ Wq,
                       const float* __restrict__ Wm,
                       unsigned short* __restrict__ wcatT, unsigned short* __restrict__ wmT)
{
  int i = blockIdx.x * 256 + threadIdx.x;
  if (i < 1024 * 512) {
    int n = i >> 9, k = i & 511;
    float v = (n < 512) ? Wv[k * 512 + n] : Wq[k * 512 + (n - 512)];
    wcatT[i] = f2bf(v);
  } else {
    int j = i - 1024 * 512;
    int n = j >> 9, k = j & 511;
    wmT[j] = f2bf(Wm[k * 512 + n]);
  }
}

// ---------------- x fp32 -> bf16 ----------------
__global__ void xcvt(const float* __restrict__ x, unsigned short* __restrict__ xb)
{
  size_t i = ((size_t)blockIdx.x * 256 + threadIdx.x) * 8;
  float4 a = *reinterpret_cast<const float4*>(&x[i]);
  float4 b = *reinterpret_cast<const float4*>(&x[i + 4]);
  uint4 d;
  d.x = pack2(a.x, a.y); d.y = pack2(a.z, a.w);
  d.z = pack2(b.x, b.y); d.w = pack2(b.z, b.w);
  *reinterpret_cast<uint4*>(&xb[i]) = d;
}

// ---------------- mm = vis * (y*a + b) ----------------
__global__ void mmk(const unsigned short* __restrict__ y, const unsigned short* __restrict__ vis,
                    const float* __restrict__ lma, const float* __restrict__ lmb,
                    unsigned short* __restrict__ mm)
{
  size_t i = ((size_t)blockIdx.x * 256 + threadIdx.x) * 8;
  int c = (int)(i & 511);
  int b = (int)(i >> 23);
  uint4 yv = *reinterpret_cast<const uint4*>(&y[i]);
  uint4 vv = *reinterpret_cast<const uint4*>(&vis[i]);
  const float* Ap = &lma[b * 512 + c];
  const float* Bp = &lmb[b * 512 + c];
  float4 a0 = *reinterpret_cast<const float4*>(Ap);
  float4 a1 = *reinterpret_cast<const float4*>(Ap + 4);
  float4 b0 = *reinterpret_cast<const float4*>(Bp);
  float4 b1 = *reinterpret_cast<const float4*>(Bp + 4);
  float m0 = bflo(vv.x) * (bflo(yv.x) * a0.x + b0.x);
  float m1 = bfhi(vv.x) * (bfhi(yv.x) * a0.y + b0.y);
  float m2 = bflo(vv.y) * (bflo(yv.y) * a0.z + b0.z);
  float m3 = bfhi(vv.y) * (bfhi(yv.y) * a0.w + b0.w);
  float m4 = bflo(vv.z) * (bflo(yv.z) * a1.x + b1.x);
  float m5 = bfhi(vv.z) * (bfhi(yv.z) * a1.y + b1.y);
  float m6 = bflo(vv.w) * (bflo(yv.w) * a1.z + b1.z);
  float m7 = bfhi(vv.w) * (bfhi(yv.w) * a1.w + b1.w);
  uint4 d;
  d.x = pack2(m0, m1); d.y = pack2(m2, m3);
  d.z = pack2(m4, m5); d.w = pack2(m6, m7);
  *reinterpret_cast<uint4*>(&mm[i]) = d;
}

// ---------------- prep: k = l@Wk+bk (fp32), v = l@Wval+bval (bf16, LINEAR layout) ----------------
__global__ void prep_kv(const float* __restrict__ l, const float* __restrict__ Wk,
                        const float* __restrict__ bk, const float* __restrict__ Wval,
                        const float* __restrict__ bval,
                        float* __restrict__ kraw, unsigned short* __restrict__ vb)
{
  int i = blockIdx.x * 256 + threadIdx.x;
  int which = i / (NB * NLANG * 512);
  int j = i - which * (NB * NLANG * 512);
  int bt = j >> 9;
  int c = j & 511;
  const float* W = which ? Wval : Wk;
  float acc = which ? bval[c] : bk[c];
  const float* lr = l + (size_t)bt * LCH;
  for (int p = 0; p < LCH; p++) acc = fmaf(lr[p], W[p * 512 + c], acc);
  if (which) vb[j] = f2bf(acc);
  else       kraw[j] = acc;
}

// ---------------- W2~T[b][n][h*32+t] = sum_d v[b][t][h*64+d] * Ww[h*64+d][n]  (bf16 out) ------
__global__ void w2prep(const unsigned short* __restrict__ vb, const float* __restrict__ Ww,
                       unsigned short* __restrict__ w2t)
{
  int i = blockIdx.x * 256 + threadIdx.x;   // NB*512*256 = 1M
  int k = i & 255;
  int n = (i >> 8) & 511;
  int b = i >> 17;
  int t = k & 31, h = k >> 5;
  float acc = 0.f;
  if (t < NLANG) {
    const unsigned short* vr = &vb[(size_t)(b * NLANG + t) * 512 + h * 64];
    const float* wr = &Ww[(size_t)(h * 64) * 512 + n];
    #pragma unroll 8
    for (int d = 0; d < 64; d++)
      acc = fmaf(__uint_as_float((unsigned)vr[d] << 16), wr[d * 512], acc);
  }
  w2t[(size_t)(b * 512 + n) * 256 + k] = f2bf(acc);
}

// ---------------- fold q-instance-norm into k' (tslot layout) ----------------
__global__ void kprep(const float* __restrict__ qsum, const float* __restrict__ qsq,
                      const float* __restrict__ kraw, unsigned short* __restrict__ kp,
                      float* __restrict__ offG)
{
  int blk = blockIdx.x; int b = blk / NLANG, t = blk - b * NLANG;
  int lane = threadIdx.x;
  float offp = 0.f;
  float vals[8];
  #pragma unroll
  for (int e = 0; e < 8; e++) {
    int c = lane * 8 + e;
    float mean = qsum[b * 512 + c] * (1.f / 16384.f);
    float var  = qsq[b * 512 + c] * (1.f / 16384.f) - mean * mean;
    float inv  = rsqrtf(var + 1e-5f);
    float a = inv * 0.044194173824159216f;
    float kv = kraw[((size_t)(b * NLANG + t)) * 512 + c];
    vals[e] = kv * a;
    offp += (-mean * a) * kv;
  }
  unsigned u0 = pack2(vals[0], vals[1]);
  unsigned u1 = pack2(vals[2], vals[3]);
  unsigned u2 = pack2(vals[4], vals[5]);
  unsigned u3 = pack2(vals[6], vals[7]);
  uint4 uu = make_uint4(u0, u1, u2, u3);
  *reinterpret_cast<uint4*>(&kp[((size_t)(b * NLANG + t)) * 512 + tslot(lane) * 8]) = uu;
  offp += __shfl_xor(offp, 1);
  offp += __shfl_xor(offp, 2);
  offp += __shfl_xor(offp, 4);
  if ((lane & 7) == 0) offG[(b * 8 + (lane >> 3)) * NLANG + t] = offp;
}

// ---------------- lang-norm coefficients ----------------
__global__ void lmk(const float* __restrict__ ysum, const float* __restrict__ ysq,
                    float* __restrict__ lma, float* __restrict__ lmb)
{
  int i = blockIdx.x * 256 + threadIdx.x;
  if (i < NB * 512) {
    float mean = ysum[i] * (1.f / 16384.f);
    float var  = ysq[i] * (1.f / 16384.f) - mean * mean;
    float inv  = rsqrtf(var + 1e-5f);
    lma[i] = inv; lmb[i] = -mean * inv;
  }
}

// ---------------- attention scores only: P~[r][h*32+t] = softmax_t(q_h . k'_h) (bf16) --------
__global__ __launch_bounds__(256, 3) void attn_k(
    const unsigned short* __restrict__ kp, const float* __restrict__ offG,
    const unsigned short* __restrict__ qb, unsigned short* __restrict__ pb)
{
  __shared__ __align__(16) unsigned short kps[NLANG * 512];
  __shared__ __align__(16) unsigned short qs[32 * 512];
  __shared__ float offs[NHEADS * NLANG];
  int tid = threadIdx.x, bid = blockIdx.x;
  int b = bid >> 9;
  int row0 = (bid & 511) * 32;
  size_t base = (size_t)b * (NLANG * 512);
  const uint4* kg = reinterpret_cast<const uint4*>(kp + base);
  uint4* kl = reinterpret_cast<uint4*>(kps);
  #pragma unroll
  for (int i = 0; i < 5; i++) { int o = i * 256 + tid; kl[o] = kg[o]; }
  if (tid < NHEADS * NLANG) offs[tid] = offG[b * (NHEADS * NLANG) + tid];

  size_t grow0 = (size_t)b * HWN + row0;
  #pragma unroll
  for (int i = 0; i < 8; i++) {
    int g = i * 256 + tid;
    int row = g >> 6, c = g & 63;
    uint4 d = *reinterpret_cast<const uint4*>(&qb[(grow0 + row) * 512 + c * 8]);
    *reinterpret_cast<uint4*>(&qs[row * 512 + tslot(c) * 8]) = d;
  }
  __syncthreads();

  int r = tid >> 3, h = tid & 7;
  float sim[NLANG];
  #pragma unroll
  for (int t = 0; t < NLANG; t++) sim[t] = offs[h * NLANG + t];
  #pragma unroll
  for (int j = 0; j < 8; j++) {
    uint4 qv = *reinterpret_cast<const uint4*>(&qs[r * 512 + (j * 8 + h) * 8]);
    float q0 = bflo(qv.x), q1 = bfhi(qv.x), q2 = bflo(qv.y), q3 = bfhi(qv.y);
    float q4 = bflo(qv.z), q5 = bfhi(qv.z), q6 = bflo(qv.w), q7 = bfhi(qv.w);
    #pragma unroll
    for (int t = 0; t < NLANG; t++) {
      uint4 kv = *reinterpret_cast<const uint4*>(&kps[t * 512 + (j * 8 + h) * 8]);
      float a = sim[t];
      a = fmaf(q0, bflo(kv.x), a); a = fmaf(q1, bfhi(kv.x), a);
      a = fmaf(q2, bflo(kv.y), a); a = fmaf(q3, bfhi(kv.y), a);
      a = fmaf(q4, bflo(kv.z), a); a = fmaf(q5, bfhi(kv.z), a);
      a = fmaf(q6, bflo(kv.w), a); a = fmaf(q7, bfhi(kv.w), a);
      sim[t] = a;
    }
  }
  float mx = sim[0];
  #pragma unroll
  for (int t = 1; t < NLANG; t++) mx = fmaxf(mx, sim[t]);
  float s = 0.f;
  #pragma unroll
  for (int t = 0; t < NLANG; t++) { float e = __expf(sim[t] - mx); sim[t] = e; s += e; }
  float invs = 1.f / s;
  #pragma unroll
  for (int t = 0; t < NLANG; t++) sim[t] *= invs;

  unsigned uu[16];
  #pragma unroll
  for (int j = 0; j < 10; j++) uu[j] = pack2(sim[2 * j], sim[2 * j + 1]);
  #pragma unroll
  for (int j = 10; j < 16; j++) uu[j] = 0u;
  size_t prow = (grow0 + r) * 256 + h * 32;
  #pragma unroll
  for (int j = 0; j < 4; j++)
    *reinterpret_cast<uint4*>(&pb[prow + j * 8]) =
        make_uint4(uu[4 * j], uu[4 * j + 1], uu[4 * j + 2], uu[4 * j + 3]);
}

// ---------------- GEMM: 128x128 tile, BK=32, 3-buf dist-2, counted vmcnt+lgkm (r9 proven) ----
// Epilogue: per-(m,n)-quad DPP 4x4 transpose -> wide writes (b64 LDS restage / float4 direct).
template<int MODE, int KD>
__global__ __launch_bounds__(256) void gemm_k(
    const unsigned short* __restrict__ A,
    const unsigned short* __restrict__ Bw,
    const float* __restrict__ bias0, const float* __restrict__ bias1,
    unsigned short* __restrict__ Out0, unsigned short* __restrict__ Out1,
    float* __restrict__ OutF,
    float* __restrict__ sum1, float* __restrict__ sum2)
{
  constexpr int GN  = (MODE == 0) ? 8 : 4;
  constexpr int NWG = (MODE == 0) ? 8192 : 4096;
  constexpr int KT  = KD / 32;
  __shared__ __align__(16) unsigned short SM[6 * 128 * 32];

  int raw = blockIdx.x;
  int lid = (raw & 7) * (NWG / 8) + (raw >> 3);
  int tileN = lid & (GN - 1);
  int tileM = lid / GN;
  int tm128 = tileM * 128;
  int b512 = (tileM >> 7) * 512;
  int tid = threadIdx.x;
  int wave = tid >> 6, lane = tid & 63;
  int wr = (wave >> 1) * 64, wc = (wave & 1) * 64;
  int r15 = lane & 15, kcg = lane >> 4;

  floatx4 acc[4][4];
  floatx4 zz = {0.f, 0.f, 0.f, 0.f};
  #pragma unroll
  for (int m = 0; m < 4; m++)
    #pragma unroll
    for (int n = 0; n < 4; n++) acc[m][n] = zz;

  const unsigned short* Arow = A + (size_t)tm128 * KD;
  const unsigned short* Brow = Bw +
      ((MODE == 1) ? (size_t)(tileM >> 7) * 512 * KD : (size_t)0) +
      (size_t)(tileN * 128) * KD;

  auto stage = [&](int kt, int s) {
    int k0 = kt * 32;
    unsigned short* As = SM + s * 4096;
    unsigned short* Bs = SM + (3 + s) * 4096;
    #pragma unroll
    for (int i = 0; i < 2; i++) {
      int idx = i * 256 + tid;
      int row = idx >> 2;
      int c = (idx & 3) ^ ((row >> 1) & 3);
      stage16(&Arow[(size_t)row * KD + k0 + c * 8],
              &As[(i * 256 + wave * 64) * 8]);
    }
    #pragma unroll
    for (int i = 0; i < 2; i++) {
      int idx = i * 256 + tid;
      int row = idx >> 2;
      int c = (idx & 3) ^ ((row >> 1) & 3);
      stage16(&Brow[(size_t)row * KD + k0 + c * 8],
              &Bs[(i * 256 + wave * 64) * 8]);
    }
  };

  stage(0, 0);
  stage(1, 1);
  #pragma unroll
  for (int kt = 0; kt < KT; kt++) {
    int s = kt % 3;
    __builtin_amdgcn_sched_barrier(0);
    if (kt < KT - 1) asm volatile("s_waitcnt vmcnt(4) lgkmcnt(0)\n\ts_barrier" ::: "memory");
    else             asm volatile("s_waitcnt vmcnt(0) lgkmcnt(0)\n\ts_barrier" ::: "memory");
    __builtin_amdgcn_sched_barrier(0);
    if (kt + 2 < KT) stage(kt + 2, (kt + 2) % 3);
    const unsigned short* As = SM + s * 4096;
    const unsigned short* Bs = SM + (3 + s) * 4096;
    short8 af[4], bfv[4];
    #pragma unroll
    for (int m = 0; m < 4; m++) {
      int R = wr + m * 16 + r15;
      af[m] = *reinterpret_cast<const short8*>(&As[R * 32 + (kcg ^ ((R >> 1) & 3)) * 8]);
    }
    #pragma unroll
    for (int n = 0; n < 4; n++) {
      int R = wc + n * 16 + r15;
      bfv[n] = *reinterpret_cast<const short8*>(&Bs[R * 32 + (kcg ^ ((R >> 1) & 3)) * 8]);
    }
    #pragma unroll
    for (int m = 0; m < 4; m++)
      #pragma unroll
      for (int n = 0; n < 4; n++)
        acc[m][n] = __builtin_amdgcn_mfma_f32_16x16x32_bf16(af[m], bfv[n], acc[m][n], 0, 0, 0);
  }

  if constexpr (MODE != 2) __syncthreads();  // SM reused as C below

  // post-transpose indices: lane holds row rowT (4 consecutive cols c4T..+3)
  int rowTl = wr + (lane >> 4) * 4 + (lane & 3);   // + m*16
  int c4Tl  = wc + ((lane >> 2) & 3) * 4;          // + n*16

  if constexpr (MODE == 2) {
    #pragma unroll
    for (int n = 0; n < 4; n++) {
      int gcol = tileN * 128 + wc + n * 16 + r15;   // original col (bias)
      #pragma unroll
      for (int m = 0; m < 4; m++) {
        float v[4];
        #pragma unroll
        for (int j = 0; j < 4; j++) v[j] = geluf(acc[m][n][j] + bias0[gcol]);
        quadT(v, lane);
        int grow = tm128 + m * 16 + rowTl;
        int gc4  = tileN * 128 + n * 16 + c4Tl;
        float4 f4; f4.x = v[0]; f4.y = v[1]; f4.z = v[2]; f4.w = v[3];
        *reinterpret_cast<float4*>(&OutF[(size_t)grow * 512 + gc4]) = f4;
      }
    }
  } else {
    unsigned short* C = SM;
    #pragma unroll
    for (int n = 0; n < 4; n++) {
      int gcol = tileN * 128 + wc + n * 16 + r15;   // original col (bias/stats)
      float s1 = 0.f, s2 = 0.f;
      #pragma unroll
      for (int m = 0; m < 4; m++) {
        float v[4];
        #pragma unroll
        for (int j = 0; j < 4; j++) v[j] = acc[m][n][j];
        if constexpr (MODE == 0) {
          if (tileN < 4) {
            #pragma unroll
            for (int j = 0; j < 4; j++) v[j] = geluf(v[j] + bias0[gcol]);
          } else {
            #pragma unroll
            for (int j = 0; j < 4; j++) { v[j] += bias1[gcol - 512]; s1 += v[j]; s2 += v[j] * v[j]; }
          }
        } else {
          #pragma unroll
          for (int j = 0; j < 4; j++) { v[j] += bias0[gcol]; s1 += v[j]; s2 += v[j] * v[j]; }
        }
        quadT(v, lane);
        int lrow = m * 16 + rowTl;
        int lc4  = n * 16 + c4Tl;
        uint2 d2; d2.x = pack2(v[0], v[1]); d2.y = pack2(v[2], v[3]);
        *reinterpret_cast<uint2*>(&C[lrow * 128 + (lc4 ^ (((lrow >> 2) & 3) << 4))]) = d2;
      }
      bool doStats = (MODE == 1) || (tileN >= 4);
      if (doStats) {
        s1 += __shfl_xor(s1, 16); s1 += __shfl_xor(s1, 32);
        s2 += __shfl_xor(s2, 16); s2 += __shfl_xor(s2, 32);
        if (lane < 16) {
          int c = (MODE == 0) ? (gcol - 512) : gcol;
          atomicAdd(&sum1[b512 + c], s1);
          atomicAdd(&sum2[b512 + c], s2);
        }
      }
    }
    __syncthreads();
    unsigned short* Og;
    int colbase;
    if constexpr (MODE == 0) {
      if (tileN < 4) { Og = Out0; colbase = tileN * 128; }
      else           { Og = Out1; colbase = (tileN - 4) * 128; }
    } else {
      Og = Out0; colbase = tileN * 128;
    }
    #pragma unroll
    for (int t = 0; t < 8; t++) {
      int cid = t * 256 + tid;
      int row = cid >> 4, cc = cid & 15;
      uint4 d = *reinterpret_cast<const uint4*>(&C[row * 128 + ((cc * 8) ^ (((row >> 2) & 3) << 4))]);
      *reinterpret_cast<uint4*>(&Og[(size_t)(tm128 + row) * 512 + colbase + cc * 8]) = d;
    }
  }
}

extern "C" void kernel_launch(void* const* d_in, const int* in_sizes, int n_in,
                              void* d_out, int out_size, void* d_ws, size_t ws_size,
                              hipStream_t stream)
{
  const float* x   = (const float*)d_in[0];
  const float* l   = (const float*)d_in[1];
  const float* Wv  = (const float*)d_in[3];
  const float* bv  = (const float*)d_in[4];
  const float* Wq  = (const float*)d_in[5];
  const float* bq  = (const float*)d_in[6];
  const float* Wk  = (const float*)d_in[7];
  const float* bk  = (const float*)d_in[8];
  const float* Wva = (const float*)d_in[9];
  const float* bva = (const float*)d_in[10];
  const float* Ww  = (const float*)d_in[11];
  const float* bw  = (const float*)d_in[12];
  const float* Wm  = (const float*)d_in[13];
  const float* bm  = (const float*)d_in[14];

  char* w = (char*)d_ws;
  size_t o = 0;
  auto alloc = [&](size_t bytes) { size_t r = o; o += (bytes + 255) & ~(size_t)255; return r; };
  size_t WCATT = alloc(1024 * 512 * 2);
  size_t WMT   = alloc(512 * 512 * 2);
  size_t W2T   = alloc((size_t)NB * 512 * 256 * 2);
  size_t KRAW  = alloc((size_t)NB * NLANG * 512 * 4);
  size_t VB    = alloc((size_t)NB * NLANG * 512 * 2);
  size_t KP    = alloc((size_t)NB * NLANG * 512 * 2);
  size_t OFFW  = alloc((size_t)NB * NHEADS * NLANG * 4);
  size_t STATS = alloc((size_t)4 * NB * 512 * 4);
  size_t LMA   = alloc((size_t)NB * 512 * 4);
  size_t LMB   = alloc((size_t)NB * 512 * 4);
  size_t XB    = alloc((size_t)MTOT * 512 * 2);  // xb; reused as mm after gemm0
  size_t VIS   = alloc((size_t)MTOT * 512 * 2);
  size_t QBUF  = alloc((size_t)MTOT * 512 * 2);
  size_t PB    = alloc((size_t)MTOT * 256 * 2);  // P~ [M][256] bf16
  size_t YBUF  = alloc((size_t)MTOT * 512 * 2);

  float* qsum = (float*)(w + STATS);
  float* qsq  = qsum + NB * 512;
  float* ysum = qsq + NB * 512;
  float* ysq  = ysum + NB * 512;

  hipMemsetAsync(w + STATS, 0, (size_t)4 * NB * 512 * 4, stream);
  prep_w<<<3072, 256, 0, stream>>>(Wv, Wq, Wm,
      (unsigned short*)(w + WCATT), (unsigned short*)(w + WMT));
  xcvt<<<32768, 256, 0, stream>>>(x, (unsigned short*)(w + XB));
  prep_kv<<<640, 256, 0, stream>>>(l, Wk, bk, Wva, bva,
      (float*)(w + KRAW), (unsigned short*)(w + VB));
  w2prep<<<4096, 256, 0, stream>>>((const unsigned short*)(w + VB), Ww,
      (unsigned short*)(w + W2T));
  gemm_k<0, 512><<<8192, 256, 0, stream>>>((const unsigned short*)(w + XB),
      (const unsigned short*)(w + WCATT), bv, bq,
      (unsigned short*)(w + VIS), (unsigned short*)(w + QBUF), nullptr, qsum, qsq);
  kprep<<<160, 64, 0, stream>>>(qsum, qsq, (const float*)(w + KRAW),
      (unsigned short*)(w + KP), (float*)(w + OFFW));
  attn_k<<<4096, 256, 0, stream>>>((const unsigned short*)(w + KP),
      (const float*)(w + OFFW), (const unsigned short*)(w + QBUF),
      (unsigned short*)(w + PB));
  gemm_k<1, 256><<<4096, 256, 0, stream>>>((const unsigned short*)(w + PB),
      (const unsigned short*)(w + W2T), bw, nullptr,
      (unsigned short*)(w + YBUF), nullptr, nullptr, ysum, ysq);
  lmk<<<16, 256, 0, stream>>>(ysum, ysq, (float*)(w + LMA), (float*)(w + LMB));
  mmk<<<32768, 256, 0, stream>>>((const unsigned short*)(w + YBUF),
      (const unsigned short*)(w + VIS), (const float*)(w + LMA), (const float*)(w + LMB),
      (unsigned short*)(w + XB));
  gemm_k<2, 512><<<4096, 256, 0, stream>>>((const unsigned short*)(w + XB),
      (const unsigned short*)(w + WMT), bm, nullptr,
      nullptr, nullptr, (float*)d_out, nullptr, nullptr);
}